// Round 3
// baseline (665.075 us; speedup 1.0000x reference)
//
#include <hip/hip_runtime.h>

#define BSHIFT 5
#define BNODES 32   // nodes per bucket

// ---------------- degree histogram ----------------
__global__ void deg_kernel(const int* __restrict__ dst, unsigned int* __restrict__ deg, int E) {
    int e = blockIdx.x * blockDim.x + threadIdx.x;
    if (e < E) atomicAdd(&deg[dst[e]], 1u);
}

// ---------------- exclusive scan of deg -> off (3-kernel hierarchical) ----------------
__global__ void chunk_sum_kernel(const unsigned int* __restrict__ deg, unsigned int* __restrict__ bsum, int N) {
    __shared__ unsigned int s[256];
    int i = blockIdx.x * 256 + threadIdx.x;
    unsigned int v = (i < N) ? deg[i] : 0u;
    s[threadIdx.x] = v; __syncthreads();
    for (int o = 128; o > 0; o >>= 1) {
        if (threadIdx.x < o) s[threadIdx.x] += s[threadIdx.x + o];
        __syncthreads();
    }
    if (threadIdx.x == 0) bsum[blockIdx.x] = s[0];
}

__global__ void scan_bsum_kernel(unsigned int* __restrict__ bsum, int nb) {
    __shared__ unsigned int s[1024];
    int t = threadIdx.x;
    unsigned int v = (t < nb) ? bsum[t] : 0u;
    s[t] = v; __syncthreads();
    for (int o = 1; o < 1024; o <<= 1) {
        unsigned int add = (t >= o) ? s[t - o] : 0u;
        __syncthreads();
        s[t] += add;
        __syncthreads();
    }
    if (t < nb) bsum[t] = s[t] - v;   // exclusive
}

// writes off[0..N-1] exclusive, and off[N] = E
__global__ void chunk_scan_kernel(const unsigned int* __restrict__ deg, const unsigned int* __restrict__ bsum,
                                  unsigned int* __restrict__ off, int N) {
    __shared__ unsigned int s[256];
    int i = blockIdx.x * 256 + threadIdx.x;
    unsigned int v = (i < N) ? deg[i] : 0u;
    s[threadIdx.x] = v; __syncthreads();
    for (int o = 1; o < 256; o <<= 1) {
        unsigned int add = (threadIdx.x >= (unsigned)o) ? s[threadIdx.x - o] : 0u;
        __syncthreads();
        s[threadIdx.x] += add;
        __syncthreads();
    }
    if (i < N) {
        off[i] = bsum[blockIdx.x] + s[threadIdx.x] - v;  // exclusive
        if (i == N - 1) off[N] = bsum[blockIdx.x] + s[threadIdx.x];  // total = E
    }
}

// ---------------- dinv + pre-scaled layer-1 feature ----------------
__global__ void dinv_ttx_kernel(const unsigned int* __restrict__ deg, const float* __restrict__ x,
                                float* __restrict__ dinv, float* __restrict__ ttx, int N) {
    int i = blockIdx.x * blockDim.x + threadIdx.x;
    if (i < N) {
        float di = 1.0f / sqrtf((float)(deg[i] + 1u));  // +1 = self loop
        dinv[i] = di;
        ttx[i] = di * x[i];
    }
}

// ---------------- bucket cursor init: cur[b] = off[b*32] ----------------
__global__ void cur_init_kernel(const unsigned int* __restrict__ off, unsigned int* __restrict__ cur, int NB) {
    int b = blockIdx.x * blockDim.x + threadIdx.x;
    if (b < NB) cur[b] = off[b << BSHIFT];
}

// ---------------- pass 1: partition edges into dst-buckets ----------------
// staged record: (dst&31)<<27 | src   (src < 2^27)
__global__ void partition_kernel(const int* __restrict__ src, const int* __restrict__ dst,
                                 unsigned int* __restrict__ cur, unsigned int* __restrict__ staged, int E) {
    int e = blockIdx.x * blockDim.x + threadIdx.x;
    if (e >= E) return;
    int d = dst[e];
    unsigned int pos = atomicAdd(&cur[d >> BSHIFT], 1u);
    staged[pos] = ((unsigned int)(d & (BNODES - 1)) << 27) | (unsigned int)src[e];
}

// ---------------- pass 2: per-bucket exact CSR placement (src only) ----------------
__global__ void build_csr_kernel(const unsigned int* __restrict__ staged, const unsigned int* __restrict__ off,
                                 unsigned int* __restrict__ csr, int N) {
    __shared__ unsigned int lcur[BNODES];
    int base = blockIdx.x << BSHIFT;
    if (threadIdx.x < BNODES) {
        int node = base + threadIdx.x;
        lcur[threadIdx.x] = (node < N) ? off[node] : 0u;
    }
    __syncthreads();
    unsigned int start = off[base];
    int endn = base + BNODES; if (endn > N) endn = N;
    unsigned int end = off[endn];
    for (unsigned int t = start + threadIdx.x; t < end; t += blockDim.x) {
        unsigned int rec = staged[t];
        unsigned int slot = atomicAdd(&lcur[rec >> 27], 1u);
        csr[slot] = rec & 0x07FFFFFFu;
    }
}

// ---------------- gathers (pre-scaled features; agg = dinv[d] * (self + sum)) ----------------
// scalar gather, 4 lanes per node
__global__ void gather1_kernel(const unsigned int* __restrict__ csr, const unsigned int* __restrict__ off,
                               const unsigned int* __restrict__ deg, const float* __restrict__ dinv,
                               const float* __restrict__ tt, float* __restrict__ agg, int N) {
    int tid = blockIdx.x * blockDim.x + threadIdx.x;
    int i = tid >> 2, l = tid & 3;
    if (i >= N) return;
    unsigned int o = off[i], n = deg[i];
    float acc = 0.f;
    for (unsigned int k = l; k < n; k += 4) acc += tt[csr[o + k]];
    acc += __shfl_xor(acc, 1, 4);
    acc += __shfl_xor(acc, 2, 4);
    if (l == 0) agg[i] = dinv[i] * (acc + tt[i]);
}

// scalar gather -> out with bias
__global__ void gather4_kernel(const unsigned int* __restrict__ csr, const unsigned int* __restrict__ off,
                               const unsigned int* __restrict__ deg, const float* __restrict__ dinv,
                               const float* __restrict__ tt, const float* __restrict__ b4,
                               float* __restrict__ out, int N) {
    int tid = blockIdx.x * blockDim.x + threadIdx.x;
    int i = tid >> 2, l = tid & 3;
    if (i >= N) return;
    unsigned int o = off[i], n = deg[i];
    float acc = 0.f;
    for (unsigned int k = l; k < n; k += 4) acc += tt[csr[o + k]];
    acc += __shfl_xor(acc, 1, 4);
    acc += __shfl_xor(acc, 2, 4);
    if (l == 0) out[i] = dinv[i] * (acc + tt[i]) + b4[0];
}

// 32-channel gather: one 32-lane group per node, unroll 4
__global__ void gather32_kernel(const unsigned int* __restrict__ csr, const unsigned int* __restrict__ off,
                                const unsigned int* __restrict__ deg, const float* __restrict__ dinv,
                                const float* __restrict__ tt, float* __restrict__ agg, int N) {
    int g = (blockIdx.x * blockDim.x + threadIdx.x) >> 5;
    int c = threadIdx.x & 31;
    if (g >= N) return;
    unsigned int o = off[g], n = deg[g];
    float acc = tt[(size_t)g * 32 + c];   // self term
    unsigned int k = 0;
    for (; k + 3 < n; k += 4) {
        unsigned int s0 = csr[o + k], s1 = csr[o + k + 1], s2 = csr[o + k + 2], s3 = csr[o + k + 3];
        float v0 = tt[(size_t)s0 * 32 + c];
        float v1 = tt[(size_t)s1 * 32 + c];
        float v2 = tt[(size_t)s2 * 32 + c];
        float v3 = tt[(size_t)s3 * 32 + c];
        acc += (v0 + v1) + (v2 + v3);
    }
    for (; k < n; ++k) acc += tt[(size_t)csr[o + k] * 32 + c];
    agg[(size_t)g * 32 + c] = dinv[g] * acc;
}

// 16-channel gather: one 16-lane group per node, unroll 4
__global__ void gather16_kernel(const unsigned int* __restrict__ csr, const unsigned int* __restrict__ off,
                                const unsigned int* __restrict__ deg, const float* __restrict__ dinv,
                                const float* __restrict__ tt, float* __restrict__ agg, int N) {
    int g = (blockIdx.x * blockDim.x + threadIdx.x) >> 4;
    int c = threadIdx.x & 15;
    if (g >= N) return;
    unsigned int o = off[g], n = deg[g];
    float acc = tt[(size_t)g * 16 + c];   // self term
    unsigned int k = 0;
    for (; k + 3 < n; k += 4) {
        unsigned int s0 = csr[o + k], s1 = csr[o + k + 1], s2 = csr[o + k + 2], s3 = csr[o + k + 3];
        float v0 = tt[(size_t)s0 * 16 + c];
        float v1 = tt[(size_t)s1 * 16 + c];
        float v2 = tt[(size_t)s2 * 16 + c];
        float v3 = tt[(size_t)s3 * 16 + c];
        acc += (v0 + v1) + (v2 + v3);
    }
    for (; k < n; ++k) acc += tt[(size_t)csr[o + k] * 16 + c];
    agg[(size_t)g * 16 + c] = dinv[g] * acc;
}

// ---------------- fused node-local transforms (write dinv-pre-scaled output) ----------------
// tt2 = dinv * (relu(agg1*W1 + b1) @ W2)
__global__ void fused12_kernel(const float* __restrict__ agg1, const float* __restrict__ dinv,
                               const float* __restrict__ W1, const float* __restrict__ b1,
                               const float* __restrict__ W2, float* __restrict__ tt2, int N) {
    __shared__ float sW1[64], sb1[64], sW2[64 * 32];
    for (int t = threadIdx.x; t < 64; t += blockDim.x) { sW1[t] = W1[t]; sb1[t] = b1[t]; }
    for (int t = threadIdx.x; t < 64 * 32; t += blockDim.x) sW2[t] = W2[t];
    __syncthreads();
    int i = blockIdx.x * 8 + (threadIdx.x >> 5);
    int c = threadIdx.x & 31;
    if (i >= N) return;
    float a = agg1[i];
    float acc = 0.f;
#pragma unroll
    for (int j = 0; j < 64; ++j) {
        float r = fmaxf(fmaf(a, sW1[j], sb1[j]), 0.f);
        acc = fmaf(r, sW2[j * 32 + c], acc);
    }
    tt2[(size_t)i * 32 + c] = dinv[i] * acc;
}

// tt3 = dinv * (relu(agg2 + b2) @ W3)
__global__ void fused23_kernel(const float* __restrict__ agg2, const float* __restrict__ dinv,
                               const float* __restrict__ b2, const float* __restrict__ W3,
                               float* __restrict__ tt3, int N) {
    __shared__ float sb2[32], sW3[32 * 16];
    for (int t = threadIdx.x; t < 32; t += blockDim.x) sb2[t] = b2[t];
    for (int t = threadIdx.x; t < 32 * 16; t += blockDim.x) sW3[t] = W3[t];
    __syncthreads();
    int i = blockIdx.x * 16 + (threadIdx.x >> 4);
    int c = threadIdx.x & 15;
    if (i >= N) return;
    float acc = 0.f;
#pragma unroll
    for (int k = 0; k < 32; ++k) {
        float r = fmaxf(agg2[(size_t)i * 32 + k] + sb2[k], 0.f);
        acc = fmaf(r, sW3[k * 16 + c], acc);
    }
    tt3[(size_t)i * 16 + c] = dinv[i] * acc;
}

// tt4 = dinv * (relu(agg3 + b3) @ W4)
__global__ void fused34_kernel(const float* __restrict__ agg3, const float* __restrict__ dinv,
                               const float* __restrict__ b3, const float* __restrict__ W4,
                               float* __restrict__ tt4, int N) {
    int i = blockIdx.x * blockDim.x + threadIdx.x;
    if (i >= N) return;
    const float4* a4 = reinterpret_cast<const float4*>(agg3 + (size_t)i * 16);
    float acc = 0.f;
#pragma unroll
    for (int q = 0; q < 4; ++q) {
        float4 v = a4[q];
        acc = fmaf(fmaxf(v.x + b3[q * 4 + 0], 0.f), W4[q * 4 + 0], acc);
        acc = fmaf(fmaxf(v.y + b3[q * 4 + 1], 0.f), W4[q * 4 + 1], acc);
        acc = fmaf(fmaxf(v.z + b3[q * 4 + 2], 0.f), W4[q * 4 + 2], acc);
        acc = fmaf(fmaxf(v.w + b3[q * 4 + 3], 0.f), W4[q * 4 + 3], acc);
    }
    tt4[i] = dinv[i] * acc;
}

extern "C" void kernel_launch(void* const* d_in, const int* in_sizes, int n_in,
                              void* d_out, int out_size, void* d_ws, size_t ws_size,
                              hipStream_t stream) {
    const float* x  = (const float*)d_in[0];
    const int* eidx = (const int*)d_in[1];
    const float* W1 = (const float*)d_in[2];
    const float* b1 = (const float*)d_in[3];
    const float* W2 = (const float*)d_in[4];
    const float* b2 = (const float*)d_in[5];
    const float* W3 = (const float*)d_in[6];
    const float* b3 = (const float*)d_in[7];
    const float* W4 = (const float*)d_in[8];
    const float* b4 = (const float*)d_in[9];
    float* out = (float*)d_out;

    const int N = in_sizes[0];         // 100000
    const int E = in_sizes[1] / 2;     // 3200000
    const int* src = eidx;
    const int* dst = eidx + E;
    const int NB = (N + BNODES - 1) >> BSHIFT;   // 3125 buckets

    char* ws = (char*)d_ws;
    unsigned int* deg  = (unsigned int*)ws;  ws += (size_t)N * 4;
    unsigned int* off  = (unsigned int*)ws;  ws += ((size_t)(N + 1) * 4 + 15) & ~15ull;
    unsigned int* bsum = (unsigned int*)ws;  ws += 4096;
    unsigned int* cur  = (unsigned int*)ws;  ws += ((size_t)NB * 4 + 15) & ~15ull;
    float* dinv = (float*)ws;                ws += (size_t)N * 4;
    float* ttx  = (float*)ws;                ws += (size_t)N * 4;
    float* agg1 = (float*)ws;                ws += (size_t)N * 4;
    float* tt4  = (float*)ws;                ws += (size_t)N * 4;
    unsigned int* staged = (unsigned int*)ws; ws += (size_t)E * 4;
    unsigned int* csr    = (unsigned int*)ws; ws += (size_t)E * 4;
    float* tt2  = (float*)ws;                ws += (size_t)N * 32 * 4;
    float* agg2 = (float*)ws;                ws += (size_t)N * 32 * 4;
    float* tt3  = tt2;                        // tt2 dead after gather32
    float* agg3 = tt2 + (size_t)N * 16;

    const int B = 256;
    const int nb = (N + 255) / 256;

    hipMemsetAsync(deg, 0, (size_t)N * 4, stream);

    deg_kernel<<<(E + B - 1) / B, B, 0, stream>>>(dst, deg, E);
    chunk_sum_kernel<<<nb, 256, 0, stream>>>(deg, bsum, N);
    scan_bsum_kernel<<<1, 1024, 0, stream>>>(bsum, nb);
    chunk_scan_kernel<<<nb, 256, 0, stream>>>(deg, bsum, off, N);
    dinv_ttx_kernel<<<(N + B - 1) / B, B, 0, stream>>>(deg, x, dinv, ttx, N);
    cur_init_kernel<<<(NB + B - 1) / B, B, 0, stream>>>(off, cur, NB);
    partition_kernel<<<(E + B - 1) / B, B, 0, stream>>>(src, dst, cur, staged, E);
    build_csr_kernel<<<NB, B, 0, stream>>>(staged, off, csr, N);

    // layer 1 (scalar) -> transform to 32ch
    gather1_kernel<<<((size_t)N * 4 + B - 1) / B, B, 0, stream>>>(csr, off, deg, dinv, ttx, agg1, N);
    fused12_kernel<<<(N + 7) / 8, B, 0, stream>>>(agg1, dinv, W1, b1, W2, tt2, N);
    // layer 2 (32ch)
    gather32_kernel<<<((size_t)N * 32 + B - 1) / B, B, 0, stream>>>(csr, off, deg, dinv, tt2, agg2, N);
    fused23_kernel<<<(N + 15) / 16, B, 0, stream>>>(agg2, dinv, b2, W3, tt3, N);
    // layer 3 (16ch)
    gather16_kernel<<<((size_t)N * 16 + B - 1) / B, B, 0, stream>>>(csr, off, deg, dinv, tt3, agg3, N);
    fused34_kernel<<<(N + B - 1) / B, B, 0, stream>>>(agg3, dinv, b3, W4, tt4, N);
    // layer 4 (scalar) -> out
    gather4_kernel<<<((size_t)N * 4 + B - 1) / B, B, 0, stream>>>(csr, off, deg, dinv, tt4, b4, out, N);
}

// Round 4
// 291.538 us; speedup vs baseline: 2.2813x; 2.2813x over previous
//
#include <hip/hip_runtime.h>

#define NPB_SHIFT 8
#define NPB 256          // nodes per bucket
#define EPB 4096         // edges per partition block
#define EPT (EPB / 256)  // edges per thread (16)
#define MAXB 512         // padded bucket count (NB = ceil(N/256) = 391)

// ---------------- K1: per-block LDS histogram of dst buckets ----------------
__global__ __launch_bounds__(256) void bucket_hist_kernel(const int* __restrict__ dst,
                                                          unsigned int* __restrict__ bhist,
                                                          int E, int NB) {
    __shared__ unsigned int h[MAXB];
    for (int j = threadIdx.x; j < MAXB; j += 256) h[j] = 0u;
    __syncthreads();
    int start = blockIdx.x * EPB;
    int cnt = min(EPB, E - start);
    for (int k = threadIdx.x; k < cnt; k += 256)
        atomicAdd(&h[((unsigned int)dst[start + k]) >> NPB_SHIFT], 1u);
    __syncthreads();
    for (int j = threadIdx.x; j < NB; j += 256) {
        unsigned int c = h[j];
        if (c) atomicAdd(&bhist[j], c);
    }
}

// ---------------- K2: single-block exclusive scan -> bbase, bcur ----------------
__global__ void bucket_scan_kernel(const unsigned int* __restrict__ bhist,
                                   unsigned int* __restrict__ bbase,
                                   unsigned int* __restrict__ bcur, int NB) {
    __shared__ unsigned int s[MAXB];
    int t = threadIdx.x;
    unsigned int v = (t < NB) ? bhist[t] : 0u;
    s[t] = v; __syncthreads();
    for (int o = 1; o < MAXB; o <<= 1) {
        unsigned int add = (t >= o) ? s[t - o] : 0u;
        __syncthreads();
        s[t] += add;
        __syncthreads();
    }
    if (t < NB) { unsigned int b = s[t] - v; bbase[t] = b; bcur[t] = b; }
}

// ---------------- K3: LDS-staged partition, coalesced bucket-grouped writes ----------------
__global__ __launch_bounds__(256) void partition_kernel(const int* __restrict__ src,
                                                        const int* __restrict__ dst,
                                                        unsigned int* __restrict__ bcur,
                                                        uint2* __restrict__ staged, int E, int NB) {
    __shared__ unsigned int hist[MAXB];
    __shared__ unsigned int sc[MAXB];
    __shared__ unsigned int lbase[MAXB];
    __shared__ unsigned int gbase[MAXB];
    __shared__ uint2 stage[EPB];
    int start = blockIdx.x * EPB;
    int cnt = min(EPB, E - start);
    for (int j = threadIdx.x; j < MAXB; j += 256) hist[j] = 0u;
    __syncthreads();

    unsigned int mysrc[EPT], mydst[EPT], myr[EPT];
#pragma unroll
    for (int u = 0; u < EPT; ++u) {
        int k = u * 256 + threadIdx.x;
        if (k < cnt) {
            unsigned int s = (unsigned int)src[start + k];
            unsigned int d = (unsigned int)dst[start + k];
            mysrc[u] = s; mydst[u] = d;
            myr[u] = atomicAdd(&hist[d >> NPB_SHIFT], 1u);
        }
    }
    __syncthreads();

    // inclusive Hillis-Steele scan of hist (512 entries, 256 threads, 2/thread)
    {
        int i0 = threadIdx.x, i1 = threadIdx.x + 256;
        sc[i0] = hist[i0]; sc[i1] = hist[i1];
        __syncthreads();
        for (int o = 1; o < MAXB; o <<= 1) {
            unsigned int v0 = (i0 >= o) ? sc[i0 - o] : 0u;
            unsigned int v1 = (i1 >= o) ? sc[i1 - o] : 0u;
            __syncthreads();
            sc[i0] += v0; sc[i1] += v1;
            __syncthreads();
        }
    }
    // reserve global ranges (one atomic per non-empty bucket) + local bases
    for (int j = threadIdx.x; j < NB; j += 256) {
        unsigned int c = hist[j];
        lbase[j] = sc[j] - c;
        gbase[j] = c ? atomicAdd(&bcur[j], c) : 0u;
    }
    __syncthreads();
    // scatter into LDS, bucket-grouped
#pragma unroll
    for (int u = 0; u < EPT; ++u) {
        int k = u * 256 + threadIdx.x;
        if (k < cnt) {
            unsigned int b = mydst[u] >> NPB_SHIFT;
            stage[lbase[b] + myr[u]] = make_uint2(mysrc[u], mydst[u]);
        }
    }
    __syncthreads();
    // coalesced copy-out: consecutive LDS slots -> consecutive global slots per bucket
    for (int t = threadIdx.x; t < cnt; t += 256) {
        uint2 r = stage[t];
        unsigned int b = r.y >> NPB_SHIFT;
        staged[(size_t)gbase[b] + (t - lbase[b])] = r;
    }
}

// ---------------- K4: per-bucket exact CSR + off/deg/dinv/ttx ----------------
__global__ __launch_bounds__(256) void build_csr_kernel(const uint2* __restrict__ staged,
                                                        const unsigned int* __restrict__ bbase,
                                                        const unsigned int* __restrict__ bhist,
                                                        const float* __restrict__ x,
                                                        unsigned int* __restrict__ csr,
                                                        unsigned int* __restrict__ off,
                                                        unsigned int* __restrict__ deg,
                                                        float* __restrict__ dinv,
                                                        float* __restrict__ ttx, int N) {
    __shared__ unsigned int cnt[NPB];
    __shared__ unsigned int loff[NPB];
    __shared__ unsigned int ncur[NPB];
    int b = blockIdx.x;
    unsigned int base = bbase[b];
    unsigned int m = bhist[b];
    int node0 = b << NPB_SHIFT;

    cnt[threadIdx.x] = 0u;
    __syncthreads();
    for (unsigned int t = threadIdx.x; t < m; t += 256)
        atomicAdd(&cnt[staged[(size_t)base + t].y & (NPB - 1)], 1u);
    __syncthreads();
    unsigned int v = cnt[threadIdx.x];
    loff[threadIdx.x] = v;
    __syncthreads();
    for (int o = 1; o < NPB; o <<= 1) {
        unsigned int a = (threadIdx.x >= (unsigned)o) ? loff[threadIdx.x - o] : 0u;
        __syncthreads();
        loff[threadIdx.x] += a;
        __syncthreads();
    }
    unsigned int ex = loff[threadIdx.x] - v;  // exclusive
    ncur[threadIdx.x] = ex;
    int node = node0 + threadIdx.x;
    if (node < N) {
        off[node] = base + ex;
        deg[node] = v;
        float di = 1.0f / sqrtf((float)(v + 1u));  // +1 self loop
        dinv[node] = di;
        ttx[node] = di * x[node];
    }
    __syncthreads();
    for (unsigned int t = threadIdx.x; t < m; t += 256) {
        uint2 r = staged[(size_t)base + t];
        unsigned int p = atomicAdd(&ncur[r.y & (NPB - 1)], 1u);
        csr[(size_t)base + p] = r.x;
    }
}

// ---------------- gathers (pre-scaled features; agg = dinv[d] * (self + sum)) ----------------
__global__ void gather1_kernel(const unsigned int* __restrict__ csr, const unsigned int* __restrict__ off,
                               const unsigned int* __restrict__ deg, const float* __restrict__ dinv,
                               const float* __restrict__ tt, float* __restrict__ agg, int N) {
    int tid = blockIdx.x * blockDim.x + threadIdx.x;
    int i = tid >> 2, l = tid & 3;
    if (i >= N) return;
    unsigned int o = off[i], n = deg[i];
    float acc = 0.f;
    for (unsigned int k = l; k < n; k += 4) acc += tt[csr[o + k]];
    acc += __shfl_xor(acc, 1, 4);
    acc += __shfl_xor(acc, 2, 4);
    if (l == 0) agg[i] = dinv[i] * (acc + tt[i]);
}

__global__ void gather4_kernel(const unsigned int* __restrict__ csr, const unsigned int* __restrict__ off,
                               const unsigned int* __restrict__ deg, const float* __restrict__ dinv,
                               const float* __restrict__ tt, const float* __restrict__ b4,
                               float* __restrict__ out, int N) {
    int tid = blockIdx.x * blockDim.x + threadIdx.x;
    int i = tid >> 2, l = tid & 3;
    if (i >= N) return;
    unsigned int o = off[i], n = deg[i];
    float acc = 0.f;
    for (unsigned int k = l; k < n; k += 4) acc += tt[csr[o + k]];
    acc += __shfl_xor(acc, 1, 4);
    acc += __shfl_xor(acc, 2, 4);
    if (l == 0) out[i] = dinv[i] * (acc + tt[i]) + b4[0];
}

__global__ void gather32_kernel(const unsigned int* __restrict__ csr, const unsigned int* __restrict__ off,
                                const unsigned int* __restrict__ deg, const float* __restrict__ dinv,
                                const float* __restrict__ tt, float* __restrict__ agg, int N) {
    int g = (blockIdx.x * blockDim.x + threadIdx.x) >> 5;
    int c = threadIdx.x & 31;
    if (g >= N) return;
    unsigned int o = off[g], n = deg[g];
    float acc = tt[(size_t)g * 32 + c];
    unsigned int k = 0;
    for (; k + 3 < n; k += 4) {
        unsigned int s0 = csr[o + k], s1 = csr[o + k + 1], s2 = csr[o + k + 2], s3 = csr[o + k + 3];
        float v0 = tt[(size_t)s0 * 32 + c];
        float v1 = tt[(size_t)s1 * 32 + c];
        float v2 = tt[(size_t)s2 * 32 + c];
        float v3 = tt[(size_t)s3 * 32 + c];
        acc += (v0 + v1) + (v2 + v3);
    }
    for (; k < n; ++k) acc += tt[(size_t)csr[o + k] * 32 + c];
    agg[(size_t)g * 32 + c] = dinv[g] * acc;
}

__global__ void gather16_kernel(const unsigned int* __restrict__ csr, const unsigned int* __restrict__ off,
                                const unsigned int* __restrict__ deg, const float* __restrict__ dinv,
                                const float* __restrict__ tt, float* __restrict__ agg, int N) {
    int g = (blockIdx.x * blockDim.x + threadIdx.x) >> 4;
    int c = threadIdx.x & 15;
    if (g >= N) return;
    unsigned int o = off[g], n = deg[g];
    float acc = tt[(size_t)g * 16 + c];
    unsigned int k = 0;
    for (; k + 3 < n; k += 4) {
        unsigned int s0 = csr[o + k], s1 = csr[o + k + 1], s2 = csr[o + k + 2], s3 = csr[o + k + 3];
        float v0 = tt[(size_t)s0 * 16 + c];
        float v1 = tt[(size_t)s1 * 16 + c];
        float v2 = tt[(size_t)s2 * 16 + c];
        float v3 = tt[(size_t)s3 * 16 + c];
        acc += (v0 + v1) + (v2 + v3);
    }
    for (; k < n; ++k) acc += tt[(size_t)csr[o + k] * 16 + c];
    agg[(size_t)g * 16 + c] = dinv[g] * acc;
}

// ---------------- fused node-local transforms (write dinv-pre-scaled output) ----------------
__global__ void fused12_kernel(const float* __restrict__ agg1, const float* __restrict__ dinv,
                               const float* __restrict__ W1, const float* __restrict__ b1,
                               const float* __restrict__ W2, float* __restrict__ tt2, int N) {
    __shared__ float sW1[64], sb1[64], sW2[64 * 32];
    for (int t = threadIdx.x; t < 64; t += blockDim.x) { sW1[t] = W1[t]; sb1[t] = b1[t]; }
    for (int t = threadIdx.x; t < 64 * 32; t += blockDim.x) sW2[t] = W2[t];
    __syncthreads();
    int i = blockIdx.x * 8 + (threadIdx.x >> 5);
    int c = threadIdx.x & 31;
    if (i >= N) return;
    float a = agg1[i];
    float acc = 0.f;
#pragma unroll
    for (int j = 0; j < 64; ++j) {
        float r = fmaxf(fmaf(a, sW1[j], sb1[j]), 0.f);
        acc = fmaf(r, sW2[j * 32 + c], acc);
    }
    tt2[(size_t)i * 32 + c] = dinv[i] * acc;
}

__global__ void fused23_kernel(const float* __restrict__ agg2, const float* __restrict__ dinv,
                               const float* __restrict__ b2, const float* __restrict__ W3,
                               float* __restrict__ tt3, int N) {
    __shared__ float sb2[32], sW3[32 * 16];
    for (int t = threadIdx.x; t < 32; t += blockDim.x) sb2[t] = b2[t];
    for (int t = threadIdx.x; t < 32 * 16; t += blockDim.x) sW3[t] = W3[t];
    __syncthreads();
    int i = blockIdx.x * 16 + (threadIdx.x >> 4);
    int c = threadIdx.x & 15;
    if (i >= N) return;
    float acc = 0.f;
#pragma unroll
    for (int k = 0; k < 32; ++k) {
        float r = fmaxf(agg2[(size_t)i * 32 + k] + sb2[k], 0.f);
        acc = fmaf(r, sW3[k * 16 + c], acc);
    }
    tt3[(size_t)i * 16 + c] = dinv[i] * acc;
}

__global__ void fused34_kernel(const float* __restrict__ agg3, const float* __restrict__ dinv,
                               const float* __restrict__ b3, const float* __restrict__ W4,
                               float* __restrict__ tt4, int N) {
    int i = blockIdx.x * blockDim.x + threadIdx.x;
    if (i >= N) return;
    const float4* a4 = reinterpret_cast<const float4*>(agg3 + (size_t)i * 16);
    float acc = 0.f;
#pragma unroll
    for (int q = 0; q < 4; ++q) {
        float4 v = a4[q];
        acc = fmaf(fmaxf(v.x + b3[q * 4 + 0], 0.f), W4[q * 4 + 0], acc);
        acc = fmaf(fmaxf(v.y + b3[q * 4 + 1], 0.f), W4[q * 4 + 1], acc);
        acc = fmaf(fmaxf(v.z + b3[q * 4 + 2], 0.f), W4[q * 4 + 2], acc);
        acc = fmaf(fmaxf(v.w + b3[q * 4 + 3], 0.f), W4[q * 4 + 3], acc);
    }
    tt4[i] = dinv[i] * acc;
}

extern "C" void kernel_launch(void* const* d_in, const int* in_sizes, int n_in,
                              void* d_out, int out_size, void* d_ws, size_t ws_size,
                              hipStream_t stream) {
    const float* x  = (const float*)d_in[0];
    const int* eidx = (const int*)d_in[1];
    const float* W1 = (const float*)d_in[2];
    const float* b1 = (const float*)d_in[3];
    const float* W2 = (const float*)d_in[4];
    const float* b2 = (const float*)d_in[5];
    const float* W3 = (const float*)d_in[6];
    const float* b3 = (const float*)d_in[7];
    const float* W4 = (const float*)d_in[8];
    const float* b4 = (const float*)d_in[9];
    float* out = (float*)d_out;

    const int N = in_sizes[0];         // 100000
    const int E = in_sizes[1] / 2;     // 3200000
    const int* src = eidx;
    const int* dst = eidx + E;
    const int NB = (N + NPB - 1) >> NPB_SHIFT;   // 391 buckets

    char* ws = (char*)d_ws;
    unsigned int* bhist = (unsigned int*)ws;  ws += MAXB * 4;
    unsigned int* bbase = (unsigned int*)ws;  ws += MAXB * 4;
    unsigned int* bcur  = (unsigned int*)ws;  ws += MAXB * 4;
    unsigned int* off   = (unsigned int*)ws;  ws += (size_t)N * 4;
    unsigned int* deg   = (unsigned int*)ws;  ws += (size_t)N * 4;
    float* dinv = (float*)ws;                 ws += (size_t)N * 4;
    float* ttx  = (float*)ws;                 ws += (size_t)N * 4;
    float* agg1 = (float*)ws;                 ws += (size_t)N * 4;
    float* tt4  = (float*)ws;                 ws += (size_t)N * 4;
    unsigned int* csr = (unsigned int*)ws;    ws += (size_t)E * 4;
    // region A: tt2 (N*32) + agg2 (N*32) = 25.6MB ; staged (E*8 = 25.6MB) ALIASES it
    float* tt2  = (float*)ws;
    float* agg2 = tt2 + (size_t)N * 32;
    uint2* staged = (uint2*)ws;               // dead before tt2 is written
    float* tt3  = tt2;                        // tt2 dead after gather32
    float* agg3 = tt2 + (size_t)N * 16;

    const int B = 256;
    const int nPartBlocks = (E + EPB - 1) / EPB;

    hipMemsetAsync(bhist, 0, MAXB * 4, stream);
    bucket_hist_kernel<<<nPartBlocks, 256, 0, stream>>>(dst, bhist, E, NB);
    bucket_scan_kernel<<<1, MAXB, 0, stream>>>(bhist, bbase, bcur, NB);
    partition_kernel<<<nPartBlocks, 256, 0, stream>>>(src, dst, bcur, staged, E, NB);
    build_csr_kernel<<<NB, 256, 0, stream>>>(staged, bbase, bhist, x, csr, off, deg, dinv, ttx, N);

    // layer 1 (scalar) -> transform to 32ch
    gather1_kernel<<<((size_t)N * 4 + B - 1) / B, B, 0, stream>>>(csr, off, deg, dinv, ttx, agg1, N);
    fused12_kernel<<<(N + 7) / 8, B, 0, stream>>>(agg1, dinv, W1, b1, W2, tt2, N);
    // layer 2 (32ch)
    gather32_kernel<<<((size_t)N * 32 + B - 1) / B, B, 0, stream>>>(csr, off, deg, dinv, tt2, agg2, N);
    fused23_kernel<<<(N + 15) / 16, B, 0, stream>>>(agg2, dinv, b2, W3, tt3, N);
    // layer 3 (16ch)
    gather16_kernel<<<((size_t)N * 16 + B - 1) / B, B, 0, stream>>>(csr, off, deg, dinv, tt3, agg3, N);
    fused34_kernel<<<(N + B - 1) / B, B, 0, stream>>>(agg3, dinv, b3, W4, tt4, N);
    // layer 4 (scalar) -> out
    gather4_kernel<<<((size_t)N * 4 + B - 1) / B, B, 0, stream>>>(csr, off, deg, dinv, tt4, b4, out, N);
}